// Round 3
// baseline (2612.369 us; speedup 1.0000x reference)
//
#include <hip/hip_runtime.h>

#define SEQ 512
#define BATCH 64
#define NN 1024
#define SS 64

// ---- transpose W1,W2 (1024x1024 f32) into workspace: Wt[i*N+j] = W[j*N+i] ----
__global__ void transpose2(const float* __restrict__ A, const float* __restrict__ Bm,
                           float* __restrict__ At, float* __restrict__ Bt) {
    __shared__ float tile[32][33];
    const float* in = blockIdx.z ? Bm : A;
    float* out      = blockIdx.z ? Bt : At;
    int bx = blockIdx.x * 32, by = blockIdx.y * 32;
    int tx = threadIdx.x, ty = threadIdx.y;   // block 32x8
#pragma unroll
    for (int r = 0; r < 32; r += 8)
        tile[ty + r][tx] = in[(by + ty + r) * NN + (bx + tx)];
    __syncthreads();
#pragma unroll
    for (int r = 0; r < 32; r += 8)
        out[(bx + ty + r) * NN + (by + tx)] = tile[tx][ty + r];
}

// ---- main LIF kernel: 1 block per batch element, thread n = neuron n ----
// Software-pipelined: pf[64] holds W1T rows for step t, loaded during step t-1.
__global__ __launch_bounds__(1024) void lif_kernel(
    const float* __restrict__ W1T, const float* __restrict__ W2T,
    const float* __restrict__ decay1, const float* __restrict__ decay2,
    const float* __restrict__ th1, const float* __restrict__ th2,
    const float* __restrict__ init1, const float* __restrict__ init2,
    const int* __restrict__ inp_ids, const int* __restrict__ inp_num,
    float* __restrict__ out)
{
    const int b = blockIdx.x;
    const int n = threadIdx.x;
    const int lane = n & 63;
    const int wid  = n >> 6;

    __shared__ int ids_buf[2][SS];
    __shared__ int s_num[2];
    __shared__ int slotsA[NN + 8];   // +8 pad so 8-wide gather can't read junk
    __shared__ int slotsB[NN + 8];
    __shared__ int wpackA[16];       // per-wave (spike_cnt | near_cnt<<16)
    __shared__ int wpackB[16];

    float v1 = init1[b * NN + n];
    float v2 = init2[b * NN + n];
    const float d1 = decay1[n], d2 = decay2[n];
    const float t1 = th1[n],    t2 = th2[n];
    const float t1b = 0.9f * t1;
    const float t2b = 0.9f * t2;
    const float omd1 = 1.0f - d1;
    const float omd2 = 1.0f - d2;

    // output layout (floats): ids1 | ids2 | cnt1 | cnt2 | st1 | st2
    float* out_ids1 = out;
    float* out_ids2 = out + (size_t)SEQ * BATCH * SS;
    float* out_cnt1 = out + (size_t)2 * SEQ * BATCH * SS;
    float* out_cnt2 = out_cnt1 + (size_t)SEQ * BATCH * 2;
    float* out_st1  = out_cnt2 + (size_t)SEQ * BATCH * 2;
    float* out_st2  = out_st1  + (size_t)SEQ * BATCH * NN;

    const unsigned long long lmask_lt = (1ull << lane) - 1ull;

    // prologue: step-0 ids/num, zero the slot pads, then issue step-0 gather
    if (n < SS) ids_buf[0][n] = inp_ids[(size_t)b * SS + n];
    if (n == 0) s_num[0] = inp_num[b];
    if (n < 8) { slotsA[NN + n] = 0; slotsB[NN + n] = 0; }
    __syncthreads();

    float pf[64];
#pragma unroll
    for (int j = 0; j < 64; ++j)
        pf[j] = W1T[(ids_buf[0][j] << 10) + n];

    for (int t = 0; t < SEQ; ++t) {
        const int cur = t & 1, nxt = cur ^ 1;
        const bool more = (t + 1 < SEQ);

        // prefetch next step's ids/num into registers (consumed pre-B1)
        int rid = 0, rnum = 0;
        if (more) {
            if (n < SS)
                rid = __builtin_nontemporal_load(&inp_ids[((size_t)(t + 1) * BATCH + b) * SS + n]);
            if (n == 0)
                rnum = __builtin_nontemporal_load(&inp_num[(t + 1) * BATCH + b]);
        }

        // ---- layer 1 current from prefetched registers ----
        const int num = s_num[cur];
        float p0 = 0.0f, p1 = 0.0f, p2 = 0.0f, p3 = 0.0f;
#pragma unroll
        for (int j = 0; j < 64; j += 4) {
            p0 += (j + 0 < num) ? pf[j + 0] : 0.0f;
            p1 += (j + 1 < num) ? pf[j + 1] : 0.0f;
            p2 += (j + 2 < num) ? pf[j + 2] : 0.0f;
            p3 += (j + 3 < num) ? pf[j + 3] : 0.0f;
        }
        const float I1 = (p0 + p1) + (p2 + p3);

        v1 = d1 * v1 + omd1 * I1;
        const bool spk1 = v1 > t1;
        const bool nr1  = v1 > t1b;
        unsigned long long bal1 = __ballot(spk1);
        unsigned long long bal2 = __ballot(nr1);
        if (lane == 0) wpackA[wid] = (int)__popcll(bal1) | ((int)__popcll(bal2) << 16);
        if (more) {
            if (n < SS) ids_buf[nxt][n] = rid;
            if (n == 0) s_num[nxt] = rnum;
        }
        __syncthreads();                                            // B1

        // ---- issue next step's W1T gather NOW; consumed at t+1's I1 ----
        if (more) {
#pragma unroll
            for (int j = 0; j < 64; ++j)
                pf[j] = W1T[(ids_buf[nxt][j] << 10) + n];
        }

        // ---- block-wide prefix from packed per-wave counts ----
        int sumP = 0, off = 0;
#pragma unroll
        for (int w = 0; w < 16; ++w) {
            int pw = wpackA[w];
            if (w < wid) off += pw & 0xFFFF;
            sumP += pw;
        }
        const int totalA  = sumP & 0xFFFF;
        const int total2A = sumP >> 16;
        const int lt1 = off + (int)__popcll(bal1 & lmask_lt);
        const int slot1 = spk1 ? lt1 : (totalA + n - lt1);
        slotsA[slot1] = n;
        __syncthreads();                                            // B2

        if (n < SS)
            __builtin_nontemporal_store((float)slotsA[n],
                                        &out_ids1[((size_t)t * BATCH + b) * SS + n]);
        if (n == 0) {
            __builtin_nontemporal_store((float)totalA,
                                        &out_cnt1[((size_t)t * BATCH + b) * 2 + 0]);
            __builtin_nontemporal_store((float)total2A,
                                        &out_cnt1[((size_t)t * BATCH + b) * 2 + 1]);
        }
        if (spk1) v1 = 0.0f;
        __builtin_nontemporal_store(v1, &out_st1[((size_t)t * BATCH + b) * NN + n]);

        // ---- layer 2: gather spiking rows (ascending slots) ----
        float I2 = 0.0f;
        for (int k0 = 0; k0 < totalA; k0 += 8) {
            float a[8];
#pragma unroll
            for (int j = 0; j < 8; ++j)
                a[j] = W2T[(slotsA[k0 + j] << 10) + n];   // pad guarantees valid index
#pragma unroll
            for (int j = 0; j < 8; ++j)
                if (k0 + j < totalA) I2 += a[j];
        }

        v2 = d2 * v2 + omd2 * I2;
        const bool spk2 = v2 > t2;
        const bool nr2  = v2 > t2b;
        unsigned long long bal3 = __ballot(spk2);
        unsigned long long bal4 = __ballot(nr2);
        if (lane == 0) wpackB[wid] = (int)__popcll(bal3) | ((int)__popcll(bal4) << 16);
        __syncthreads();                                            // B3

        int sumQ = 0, offB = 0;
#pragma unroll
        for (int w = 0; w < 16; ++w) {
            int pw = wpackB[w];
            if (w < wid) offB += pw & 0xFFFF;
            sumQ += pw;
        }
        const int totalB  = sumQ & 0xFFFF;
        const int total2B = sumQ >> 16;
        const int lt2 = offB + (int)__popcll(bal3 & lmask_lt);
        const int slot2 = spk2 ? lt2 : (totalB + n - lt2);
        slotsB[slot2] = n;
        __syncthreads();                                            // B4

        if (n < SS)
            __builtin_nontemporal_store((float)slotsB[n],
                                        &out_ids2[((size_t)t * BATCH + b) * SS + n]);
        if (n == 0) {
            __builtin_nontemporal_store((float)totalB,
                                        &out_cnt2[((size_t)t * BATCH + b) * 2 + 0]);
            __builtin_nontemporal_store((float)total2B,
                                        &out_cnt2[((size_t)t * BATCH + b) * 2 + 1]);
        }
        if (spk2) v2 = 0.0f;
        __builtin_nontemporal_store(v2, &out_st2[((size_t)t * BATCH + b) * NN + n]);
    }
}

extern "C" void kernel_launch(void* const* d_in, const int* in_sizes, int n_in,
                              void* d_out, int out_size, void* d_ws, size_t ws_size,
                              hipStream_t stream) {
    const float* W1     = (const float*)d_in[0];
    const float* W2     = (const float*)d_in[1];
    const float* decay1 = (const float*)d_in[2];
    const float* decay2 = (const float*)d_in[3];
    const float* th1    = (const float*)d_in[4];
    const float* th2    = (const float*)d_in[5];
    const float* init1  = (const float*)d_in[6];
    const float* init2  = (const float*)d_in[7];
    const int* inp_ids  = (const int*)d_in[8];
    const int* inp_num  = (const int*)d_in[9];
    float* out = (float*)d_out;

    float* W1T = (float*)d_ws;
    float* W2T = W1T + (size_t)NN * NN;

    dim3 tb(32, 8, 1), tg(NN / 32, NN / 32, 2);
    transpose2<<<tg, tb, 0, stream>>>(W1, W2, W1T, W2T);
    lif_kernel<<<BATCH, NN, 0, stream>>>(W1T, W2T, decay1, decay2, th1, th2,
                                         init1, init2, inp_ids, inp_num, out);
}

// Round 4
// 1941.232 us; speedup vs baseline: 1.3457x; 1.3457x over previous
//
#include <hip/hip_runtime.h>

#define SEQ 512
#define BATCH 64
#define NN 1024
#define SS 64

// ---- transpose W1,W2 (1024x1024 f32) into workspace: Wt[i*N+j] = W[j*N+i] ----
__global__ void transpose2(const float* __restrict__ A, const float* __restrict__ Bm,
                           float* __restrict__ At, float* __restrict__ Bt) {
    __shared__ float tile[32][33];
    const float* in = blockIdx.z ? Bm : A;
    float* out      = blockIdx.z ? Bt : At;
    int bx = blockIdx.x * 32, by = blockIdx.y * 32;
    int tx = threadIdx.x, ty = threadIdx.y;   // block 32x8
#pragma unroll
    for (int r = 0; r < 32; r += 8)
        tile[ty + r][tx] = in[(by + ty + r) * NN + (bx + tx)];
    __syncthreads();
#pragma unroll
    for (int r = 0; r < 32; r += 8)
        out[(bx + ty + r) * NN + (by + tx)] = tile[tx][ty + r];
}

// block-wide (16-wave) packed prefix: wp[16] in LDS -> (off = sum w<wid, total)
__device__ __forceinline__ int prefix16(const volatile int* wp, int lane, int wid, int& total) {
    int sc = wp[lane & 15];
    int t;
    t = __shfl_up(sc, 1, 16); if ((lane & 15) >= 1) sc += t;
    t = __shfl_up(sc, 2, 16); if ((lane & 15) >= 2) sc += t;
    t = __shfl_up(sc, 4, 16); if ((lane & 15) >= 4) sc += t;
    t = __shfl_up(sc, 8, 16); if ((lane & 15) >= 8) sc += t;
    total = __shfl(sc, 15, 16);
    int off = __shfl(sc, (wid == 0) ? 0 : (wid - 1), 16);
    return (wid == 0) ? 0 : off;
}

// ---- main LIF kernel: 1 block/batch, thread n = neuron n, 1 barrier/step ----
__global__ __launch_bounds__(1024, 4) void lif_kernel(
    const float* __restrict__ W1T, const float* __restrict__ W2T,
    const float* __restrict__ decay1, const float* __restrict__ decay2,
    const float* __restrict__ th1, const float* __restrict__ th2,
    const float* __restrict__ init1, const float* __restrict__ init2,
    const int* __restrict__ inp_ids, const int* __restrict__ inp_num,
    float* __restrict__ out)
{
    const int b = blockIdx.x;
    const int n = threadIdx.x;
    const int lane = n & 63;
    const int wid  = n >> 6;

    __shared__ unsigned long long sh_bal1[2][16];
    __shared__ int wpackA[2][16];
    __shared__ int wpackB[2][16];
    __shared__ int ids_buf[2][SS];
    __shared__ int s_num[2];
    __shared__ int idlist1[2][SS];
    __shared__ int idlist2[2][SS];

    float v1 = init1[b * NN + n];
    float v2 = init2[b * NN + n];
    const float d1 = decay1[n], d2 = decay2[n];
    const float t1 = th1[n],    t2 = th2[n];
    const float t1b = 0.9f * t1, t2b = 0.9f * t2;
    const float omd1 = 1.0f - d1, omd2 = 1.0f - d2;

    // output layout (floats): ids1 | ids2 | cnt1 | cnt2 | st1 | st2
    float* out_ids1 = out;
    float* out_ids2 = out + (size_t)SEQ * BATCH * SS;
    float* out_cnt1 = out + (size_t)2 * SEQ * BATCH * SS;
    float* out_cnt2 = out_cnt1 + (size_t)SEQ * BATCH * 2;
    float* out_st1  = out_cnt2 + (size_t)SEQ * BATCH * 2;
    float* out_st2  = out_st1  + (size_t)SEQ * BATCH * NN;

    const unsigned long long lmask = (1ull << lane) - 1ull;

    // prologue: ids/num for step 0, then issue step-0 gather
    if (n < SS) ids_buf[0][n] = inp_ids[(size_t)b * SS + n];
    if (n == 0) s_num[0] = inp_num[b];
    __syncthreads();

    float pf[64];
#pragma unroll
    for (int j = 0; j < 64; ++j) pf[j] = 0.0f;
    {
        const int nc = s_num[0];
#pragma unroll
        for (int c = 0; c < 4; ++c)
            if (nc > c * 16) {
#pragma unroll
                for (int j = 0; j < 16; ++j)
                    pf[c * 16 + j] = W1T[(ids_buf[0][c * 16 + j] << 10) + n];
            }
    }

    unsigned long long bal3p = 0ull;   // previous step's layer-2 spike ballot

    for (int i = 0; i < SEQ; ++i) {
        const int p = i & 1, q = p ^ 1;

        // ================= segment P : layer 1 of step i =================
        int rid = 0, rnum = 0;
        if (i + 1 < SEQ) {
            if (n < SS)
                rid = __builtin_nontemporal_load(&inp_ids[((size_t)(i + 1) * BATCH + b) * SS + n]);
            if (n == 0)
                rnum = __builtin_nontemporal_load(&inp_num[(i + 1) * BATCH + b]);
        }

        const int num = s_num[p];
        const int nf  = num >> 4;      // # full 16-chunks (0..3)
        const int rem = num & 15;
        float c0 = 0.0f, c1 = 0.0f, c2 = 0.0f, c3 = 0.0f;
        // chunk 0
        if (nf > 0) {
#pragma unroll
            for (int j = 0; j < 16; ++j) c0 += pf[j];
        } else if (rem) {
#pragma unroll
            for (int j = 0; j < 16; ++j) c0 += (j < rem) ? pf[j] : 0.0f;
        }
        // chunk 1
        if (nf > 1) {
#pragma unroll
            for (int j = 0; j < 16; ++j) c1 += pf[16 + j];
        } else if (nf == 1 && rem) {
#pragma unroll
            for (int j = 0; j < 16; ++j) c1 += (j < rem) ? pf[16 + j] : 0.0f;
        }
        // chunk 2
        if (nf > 2) {
#pragma unroll
            for (int j = 0; j < 16; ++j) c2 += pf[32 + j];
        } else if (nf == 2 && rem) {
#pragma unroll
            for (int j = 0; j < 16; ++j) c2 += (j < rem) ? pf[32 + j] : 0.0f;
        }
        // chunk 3
        if (nf > 3) {
#pragma unroll
            for (int j = 0; j < 16; ++j) c3 += pf[48 + j];
        } else if (nf == 3 && rem) {
#pragma unroll
            for (int j = 0; j < 16; ++j) c3 += (j < rem) ? pf[48 + j] : 0.0f;
        }
        const float I1 = (c0 + c1) + (c2 + c3);

        v1 = d1 * v1 + omd1 * I1;
        const bool spk1 = v1 > t1;
        const unsigned long long bal1 = __ballot(spk1);
        const unsigned long long bal2 = __ballot(v1 > t1b);
        if (lane == 0) {
            sh_bal1[p][wid] = bal1;
            wpackA[p][wid]  = (int)__popcll(bal1) | ((int)__popcll(bal2) << 16);
        }
        if (i + 1 < SEQ) {
            if (n < SS) ids_buf[q][n] = rid;
            if (n == 0) s_num[q] = rnum;
        }
        if (spk1) v1 = 0.0f;

        __syncthreads();                                   // the ONE barrier of step i

        // ================= segment Q =================
        // issue W1T gather for step i+1 (consumed at P(i+1); no barrier in between)
        if (i + 1 < SEQ) {
            const int nn2 = s_num[q];
            const int* idn = ids_buf[q];
#pragma unroll
            for (int c = 0; c < 4; ++c)
                if (nn2 > c * 16) {
#pragma unroll
                    for (int j = 0; j < 16; ++j)
                        pf[c * 16 + j] = W1T[(idn[c * 16 + j] << 10) + n];
                }
        }

        // layer-1 slot machinery + outputs for step i
        int sum1;
        const int off1 = prefix16(wpackA[p], lane, wid, sum1);
        const int totalA = sum1 & 0xFFFF;
        const int r1 = (off1 & 0xFFFF) + (int)__popcll(bal1 & lmask);
        const int slot1 = spk1 ? r1 : (totalA + n - r1);
        if (slot1 < SS) idlist1[p][slot1] = n;

        __builtin_nontemporal_store(v1, &out_st1[((size_t)i * BATCH + b) * NN + n]);
        if (n == 0) {
            __builtin_nontemporal_store((float)totalA, &out_cnt1[((size_t)i * BATCH + b) * 2 + 0]);
            __builtin_nontemporal_store((float)(sum1 >> 16), &out_cnt1[((size_t)i * BATCH + b) * 2 + 1]);
        }
        if (i > 0 && n < SS)
            __builtin_nontemporal_store((float)idlist1[q][n],
                                        &out_ids1[((size_t)(i - 1) * BATCH + b) * SS + n]);

        // layer 2 of step i: decode spike ballots, gather W2T rows ascending
        float I2 = 0.0f;
        if (totalA > 0) {
#pragma unroll 1
            for (int w = 0; w < 16; ++w) {
                unsigned long long m = sh_bal1[p][w];
                while (m) {
                    const int j = __builtin_ctzll(m);
                    m &= m - 1;
                    I2 += W2T[(((w << 6) + j) << 10) + n];
                }
            }
        }
        v2 = d2 * v2 + omd2 * I2;
        const bool spk2 = v2 > t2;
        const unsigned long long bal3 = __ballot(spk2);
        const unsigned long long bal4 = __ballot(v2 > t2b);
        if (lane == 0) wpackB[p][wid] = (int)__popcll(bal3) | ((int)__popcll(bal4) << 16);
        if (spk2) v2 = 0.0f;
        __builtin_nontemporal_store(v2, &out_st2[((size_t)i * BATCH + b) * NN + n]);

        // deferred layer-2 slot machinery for step i-1 (wpackB[q] published at BAR(i))
        if (i > 0) {
            int sum2;
            const int off2 = prefix16(wpackB[q], lane, wid, sum2);
            const int totalB = sum2 & 0xFFFF;
            const int r2 = (off2 & 0xFFFF) + (int)__popcll(bal3p & lmask);
            const bool spk2p = (bal3p >> lane) & 1ull;
            const int slot2 = spk2p ? r2 : (totalB + n - r2);
            if (slot2 < SS) idlist2[q][slot2] = n;
            if (n == 0) {
                __builtin_nontemporal_store((float)totalB,
                                            &out_cnt2[((size_t)(i - 1) * BATCH + b) * 2 + 0]);
                __builtin_nontemporal_store((float)(sum2 >> 16),
                                            &out_cnt2[((size_t)(i - 1) * BATCH + b) * 2 + 1]);
            }
            if (i > 1 && n < SS)
                __builtin_nontemporal_store((float)idlist2[p][n],
                                            &out_ids2[((size_t)(i - 2) * BATCH + b) * SS + n]);
        }
        bal3p = bal3;
    }

    // ================= epilogue =================
    const int pl = (SEQ - 1) & 1;      // parity of last step
    const int ql = pl ^ 1;
    __syncthreads();   // publish idlist1[pl], wpackB[pl], idlist2[ql]
    if (n < SS) {
        __builtin_nontemporal_store((float)idlist1[pl][n],
                                    &out_ids1[((size_t)(SEQ - 1) * BATCH + b) * SS + n]);
        __builtin_nontemporal_store((float)idlist2[ql][n],
                                    &out_ids2[((size_t)(SEQ - 2) * BATCH + b) * SS + n]);
    }
    {
        int sum2;
        const int off2 = prefix16(wpackB[pl], lane, wid, sum2);
        const int totalB = sum2 & 0xFFFF;
        const int r2 = (off2 & 0xFFFF) + (int)__popcll(bal3p & lmask);
        const bool spk2p = (bal3p >> lane) & 1ull;
        const int slot2 = spk2p ? r2 : (totalB + n - r2);
        if (slot2 < SS) idlist2[pl][slot2] = n;
        if (n == 0) {
            __builtin_nontemporal_store((float)totalB,
                                        &out_cnt2[((size_t)(SEQ - 1) * BATCH + b) * 2 + 0]);
            __builtin_nontemporal_store((float)(sum2 >> 16),
                                        &out_cnt2[((size_t)(SEQ - 1) * BATCH + b) * 2 + 1]);
        }
    }
    __syncthreads();
    if (n < SS)
        __builtin_nontemporal_store((float)idlist2[pl][n],
                                    &out_ids2[((size_t)(SEQ - 1) * BATCH + b) * SS + n]);
}

extern "C" void kernel_launch(void* const* d_in, const int* in_sizes, int n_in,
                              void* d_out, int out_size, void* d_ws, size_t ws_size,
                              hipStream_t stream) {
    const float* W1     = (const float*)d_in[0];
    const float* W2     = (const float*)d_in[1];
    const float* decay1 = (const float*)d_in[2];
    const float* decay2 = (const float*)d_in[3];
    const float* th1    = (const float*)d_in[4];
    const float* th2    = (const float*)d_in[5];
    const float* init1  = (const float*)d_in[6];
    const float* init2  = (const float*)d_in[7];
    const int* inp_ids  = (const int*)d_in[8];
    const int* inp_num  = (const int*)d_in[9];
    float* out = (float*)d_out;

    float* W1T = (float*)d_ws;
    float* W2T = W1T + (size_t)NN * NN;

    dim3 tb(32, 8, 1), tg(NN / 32, NN / 32, 2);
    transpose2<<<tg, tb, 0, stream>>>(W1, W2, W1T, W2T);
    lif_kernel<<<BATCH, NN, 0, stream>>>(W1T, W2T, decay1, decay2, th1, th2,
                                         init1, init2, inp_ids, inp_num, out);
}